// Round 1
// baseline (990.744 us; speedup 1.0000x reference)
//
#include <hip/hip_runtime.h>
#include <math.h>

// Problem constants
#define N_T   16
#define BSZ   128
#define DDIM  4096
#define KROWS (N_T * BSZ)          // 2048
#define CHW   (3 * 64 * 64)        // 12288
#define S_PIC (BSZ * CHW)          // 1572864
#define T_MSE (N_T * S_PIC)        // 25165824
#define KPOS  (KROWS * (N_T - 1))  // 30720

// ---------------- reductions ----------------
__device__ __forceinline__ float waveReduceSum(float v) {
    for (int off = 32; off > 0; off >>= 1) v += __shfl_down(v, off, 64);
    return v;
}
__device__ __forceinline__ float waveReduceMax(float v) {
    for (int off = 32; off > 0; off >>= 1) v = fmaxf(v, __shfl_down(v, off, 64));
    return v;
}
__device__ __forceinline__ float blockReduceSum(float v) {
    __shared__ float s[8];
    int lane = threadIdx.x & 63, wid = threadIdx.x >> 6;
    v = waveReduceSum(v);
    if (lane == 0) s[wid] = v;
    __syncthreads();
    int nw = (blockDim.x + 63) >> 6;
    v = (threadIdx.x < nw) ? s[threadIdx.x] : 0.0f;
    if (wid == 0) v = waveReduceSum(v);
    return v;   // valid in thread 0
}
__device__ __forceinline__ float blockReduceMax(float v) {
    __shared__ float s[8];
    int lane = threadIdx.x & 63, wid = threadIdx.x >> 6;
    v = waveReduceMax(v);
    if (lane == 0) s[wid] = v;
    __syncthreads();
    int nw = (blockDim.x + 63) >> 6;
    v = (threadIdx.x < nw) ? s[threadIdx.x] : -INFINITY;
    if (wid == 0) v = waveReduceMax(v);
    return v;   // valid in thread 0
}

// ---------------- K1: MSE with cyclic shift ----------------
__global__ void mse_kernel(const float* __restrict__ pic,
                           const float* __restrict__ dec,
                           float* __restrict__ acc) {
    const int total4 = T_MSE / 4;
    float sum = 0.0f;
    for (int t = blockIdx.x * blockDim.x + threadIdx.x; t < total4;
         t += gridDim.x * blockDim.x) {
        int base = t * 4;
        int n    = base / S_PIC;                  // const divide -> magic mul
        int rest = base - n * S_PIC;
        const float4 p = *(const float4*)(pic + base);
        const float4 d = *(const float4*)(dec + ((n + 1) & (N_T - 1)) * S_PIC + rest);
        float dx = p.x - d.x, dy = p.y - d.y, dz = p.z - d.z, dw = p.w - d.w;
        sum += dx * dx + dy * dy + dz * dz + dw * dw;
    }
    sum = blockReduceSum(sum);
    if (threadIdx.x == 0) atomicAdd(acc, sum);
}

// ---------------- K2: in-place row normalization of h ----------------
__global__ void norm_kernel(float* __restrict__ h) {
    const int row = blockIdx.x;
    float* r = h + (long long)row * DDIM;
    float ss = 0.0f;
    for (int k = threadIdx.x * 4; k < DDIM; k += blockDim.x * 4) {
        float4 v = *(const float4*)(r + k);
        ss += v.x * v.x + v.y * v.y + v.z * v.z + v.w * v.w;
    }
    ss = blockReduceSum(ss);
    __shared__ float scale_s;
    if (threadIdx.x == 0) scale_s = 1.0f / fmaxf(sqrtf(ss), 1e-8f);
    __syncthreads();
    const float sc = scale_s;
    for (int k = threadIdx.x * 4; k < DDIM; k += blockDim.x * 4) {
        float4 v = *(const float4*)(r + k);
        v.x *= sc; v.y *= sc; v.z *= sc; v.w *= sc;
        *(float4*)(r + k) = v;
    }
}

// ---------------- K3: fp32 tiled GEMM  S = 2 * X @ X^T ----------------
// X: KROWS x DDIM row-major.  C: KROWS x KROWS row-major.
#define BM 128
#define BN 128
#define BK 16
__global__ __launch_bounds__(256) void gemm_kernel(const float* __restrict__ X,
                                                   float* __restrict__ C) {
    __shared__ float As[BM][BK + 1];
    __shared__ float Bs[BN][BK + 1];
    const int bi = blockIdx.y, bj = blockIdx.x;
    const int tid = threadIdx.x;
    const int tx = tid & 15, ty = tid >> 4;

    float acc[8][8];
#pragma unroll
    for (int r = 0; r < 8; r++)
#pragma unroll
        for (int c = 0; c < 8; c++) acc[r][c] = 0.0f;

    // Each thread stages 8 floats (2x float4) per matrix per k-tile.
    const int lrow = tid >> 1;           // 0..127
    const int lcol = (tid & 1) * 8;      // 0 or 8
    const float* Ag = X + (long long)(bi * BM + lrow) * DDIM + lcol;
    const float* Bg = X + (long long)(bj * BN + lrow) * DDIM + lcol;

    for (int kk = 0; kk < DDIM; kk += BK) {
        float4 a0 = *(const float4*)(Ag + kk);
        float4 a1 = *(const float4*)(Ag + kk + 4);
        float4 b0 = *(const float4*)(Bg + kk);
        float4 b1 = *(const float4*)(Bg + kk + 4);
        __syncthreads();
        // scalar stores (pitch 17 is unaligned for float4, but conflict-free)
        As[lrow][lcol + 0] = a0.x; As[lrow][lcol + 1] = a0.y;
        As[lrow][lcol + 2] = a0.z; As[lrow][lcol + 3] = a0.w;
        As[lrow][lcol + 4] = a1.x; As[lrow][lcol + 5] = a1.y;
        As[lrow][lcol + 6] = a1.z; As[lrow][lcol + 7] = a1.w;
        Bs[lrow][lcol + 0] = b0.x; Bs[lrow][lcol + 1] = b0.y;
        Bs[lrow][lcol + 2] = b0.z; Bs[lrow][lcol + 3] = b0.w;
        Bs[lrow][lcol + 4] = b1.x; Bs[lrow][lcol + 5] = b1.y;
        Bs[lrow][lcol + 6] = b1.z; Bs[lrow][lcol + 7] = b1.w;
        __syncthreads();
#pragma unroll
        for (int k = 0; k < BK; k++) {
            float a[8], b[8];
#pragma unroll
            for (int r = 0; r < 8; r++) a[r] = As[ty * 8 + r][k];
#pragma unroll
            for (int c = 0; c < 8; c++) b[c] = Bs[tx * 8 + c][k];
#pragma unroll
            for (int r = 0; r < 8; r++)
#pragma unroll
                for (int c = 0; c < 8; c++) acc[r][c] += a[r] * b[c];
        }
    }

    // epilogue: C = 2 * acc  (the /TEMP with TEMP=0.5)
#pragma unroll
    for (int r = 0; r < 8; r++) {
        const int row = bi * BM + ty * 8 + r;
        float* out = C + (long long)row * KROWS + bj * BN + tx * 8;
#pragma unroll
        for (int c = 0; c < 8; c += 4) {
            float4 v;
            v.x = 2.0f * acc[r][c + 0];
            v.y = 2.0f * acc[r][c + 1];
            v.z = 2.0f * acc[r][c + 2];
            v.w = 2.0f * acc[r][c + 3];
            *(float4*)(out + c) = v;
        }
    }
}

// ---------------- K4: per-row masked LSE + positives ----------------
__global__ void lse_kernel(const float* __restrict__ C, float* __restrict__ acc) {
    const int i = blockIdx.x;
    __shared__ float srow[KROWS];      // 8 KB
    const float* row = C + (long long)i * KROWS;
    for (int j = threadIdx.x; j < KROWS; j += blockDim.x) srow[j] = row[j];
    __syncthreads();

    const int ires = i & (BSZ - 1);
    // pass 1: max over negatives (j % BSZ != ires)
    float m = -INFINITY;
    for (int j = threadIdx.x; j < KROWS; j += blockDim.x)
        if ((j & (BSZ - 1)) != ires) m = fmaxf(m, srow[j]);
    m = blockReduceMax(m);
    __shared__ float mS;
    if (threadIdx.x == 0) mS = m;
    __syncthreads();
    m = mS;
    // pass 2: sum exp
    float se = 0.0f;
    for (int j = threadIdx.x; j < KROWS; j += blockDim.x)
        if ((j & (BSZ - 1)) != ires) se += expf(srow[j] - m);
    se = blockReduceSum(se);

    if (threadIdx.x == 0) {
        const float neg_lse = m + logf(se);
        float loss = 0.0f;
#pragma unroll
        for (int t = 0; t < N_T; t++) {
            const int j = ires + t * BSZ;
            if (j == i) continue;
            const float x = neg_lse - srow[j];   // logaddexp(L,p)-p = softplus(L-p)
            loss += (x > 0.0f) ? (x + log1pf(expf(-x))) : log1pf(expf(x));
        }
        atomicAdd(acc + 1, loss);
    }
}

// ---------------- K5: finalize ----------------
__global__ void finalize_kernel(const float* __restrict__ acc, float* __restrict__ out) {
    if (threadIdx.x == 0 && blockIdx.x == 0)
        out[0] = acc[0] / (float)T_MSE + acc[1] / (float)KPOS;
}

extern "C" void kernel_launch(void* const* d_in, const int* in_sizes, int n_in,
                              void* d_out, int out_size, void* d_ws, size_t ws_size,
                              hipStream_t stream) {
    const float* pic = (const float*)d_in[0];
    float* dec = (float*)d_in[1];        // may be reused as scratch after K1 reads it
    float* h   = (float*)d_in[2];        // normalized in place (restored each launch)
    float* out = (float*)d_out;

    float* acc = (float*)d_ws;           // acc[0]=mse_sum, acc[1]=loss_h_sum
    const size_t simmat_bytes = (size_t)KROWS * KROWS * sizeof(float);
    float* simmat;
    if (ws_size >= 256 + simmat_bytes) {
        simmat = (float*)((char*)d_ws + 256);
    } else {
        // dec_pics buffer (100 MB) as scratch: fully consumed by mse_kernel
        // before gemm_kernel writes it; inputs are restored before every launch.
        simmat = dec;
    }

    hipMemsetAsync(d_ws, 0, 256, stream);
    mse_kernel<<<2048, 256, 0, stream>>>(pic, dec, acc);
    norm_kernel<<<KROWS, 256, 0, stream>>>(h);
    dim3 ggrid(KROWS / BN, KROWS / BM);
    gemm_kernel<<<ggrid, 256, 0, stream>>>(h, simmat);
    lse_kernel<<<KROWS, 256, 0, stream>>>(simmat, acc);
    finalize_kernel<<<1, 64, 0, stream>>>(acc, out);
}

// Round 2
// 360.187 us; speedup vs baseline: 2.7506x; 2.7506x over previous
//
#include <hip/hip_runtime.h>
#include <hip/hip_bf16.h>
#include <math.h>

// Problem constants
#define N_T   16
#define BSZ   128
#define DDIM  4096
#define KROWS (N_T * BSZ)          // 2048
#define CHW   (3 * 64 * 64)        // 12288
#define S_PIC (BSZ * CHW)          // 1572864
#define T_MSE (N_T * S_PIC)        // 25165824
#define KPOS  (KROWS * (N_T - 1))  // 30720

typedef short  bf16x8 __attribute__((ext_vector_type(8)));   // 8 bf16 = 4 VGPRs
typedef float  f32x4  __attribute__((ext_vector_type(4)));

// ---------------- reductions ----------------
__device__ __forceinline__ float waveReduceSum(float v) {
    for (int off = 32; off > 0; off >>= 1) v += __shfl_down(v, off, 64);
    return v;
}
__device__ __forceinline__ float waveReduceMax(float v) {
    for (int off = 32; off > 0; off >>= 1) v = fmaxf(v, __shfl_down(v, off, 64));
    return v;
}
__device__ __forceinline__ float blockReduceSum(float v) {
    __shared__ float s[8];
    int lane = threadIdx.x & 63, wid = threadIdx.x >> 6;
    v = waveReduceSum(v);
    if (lane == 0) s[wid] = v;
    __syncthreads();
    int nw = (blockDim.x + 63) >> 6;
    v = (threadIdx.x < nw) ? s[threadIdx.x] : 0.0f;
    if (wid == 0) v = waveReduceSum(v);
    return v;   // valid in thread 0
}
__device__ __forceinline__ float blockReduceMax(float v) {
    __shared__ float s[8];
    int lane = threadIdx.x & 63, wid = threadIdx.x >> 6;
    v = waveReduceMax(v);
    if (lane == 0) s[wid] = v;
    __syncthreads();
    int nw = (blockDim.x + 63) >> 6;
    v = (threadIdx.x < nw) ? s[threadIdx.x] : -INFINITY;
    if (wid == 0) v = waveReduceMax(v);
    return v;   // valid in thread 0
}

// ---------------- K1: MSE with cyclic shift ----------------
__global__ void mse_kernel(const float* __restrict__ pic,
                           const float* __restrict__ dec,
                           float* __restrict__ acc) {
    const int total4 = T_MSE / 4;
    float sum = 0.0f;
    for (int t = blockIdx.x * blockDim.x + threadIdx.x; t < total4;
         t += gridDim.x * blockDim.x) {
        int base = t * 4;
        int n    = base / S_PIC;
        int rest = base - n * S_PIC;
        const float4 p = *(const float4*)(pic + base);
        const float4 d = *(const float4*)(dec + ((n + 1) & (N_T - 1)) * S_PIC + rest);
        float dx = p.x - d.x, dy = p.y - d.y, dz = p.z - d.z, dw = p.w - d.w;
        sum += dx * dx + dy * dy + dz * dz + dw * dw;
    }
    sum = blockReduceSum(sum);
    if (threadIdx.x == 0) atomicAdd(acc, sum);
}

// ---------------- K2: row normalization of h -> bf16 ----------------
__global__ void norm_kernel(const float* __restrict__ h,
                            __hip_bfloat16* __restrict__ hb) {
    const int row = blockIdx.x;
    const float* r = h + (size_t)row * DDIM;
    float ss = 0.0f;
    for (int k = threadIdx.x * 8; k < DDIM; k += blockDim.x * 8) {
        float4 v0 = *(const float4*)(r + k);
        float4 v1 = *(const float4*)(r + k + 4);
        ss += v0.x * v0.x + v0.y * v0.y + v0.z * v0.z + v0.w * v0.w;
        ss += v1.x * v1.x + v1.y * v1.y + v1.z * v1.z + v1.w * v1.w;
    }
    ss = blockReduceSum(ss);
    __shared__ float scale_s;
    if (threadIdx.x == 0) scale_s = 1.0f / fmaxf(sqrtf(ss), 1e-8f);
    __syncthreads();
    const float sc = scale_s;
    __hip_bfloat16* ob = hb + (size_t)row * DDIM;
    for (int k = threadIdx.x * 8; k < DDIM; k += blockDim.x * 8) {
        float4 v0 = *(const float4*)(r + k);
        float4 v1 = *(const float4*)(r + k + 4);
        __hip_bfloat16 t[8];
        t[0] = __float2bfloat16(v0.x * sc); t[1] = __float2bfloat16(v0.y * sc);
        t[2] = __float2bfloat16(v0.z * sc); t[3] = __float2bfloat16(v0.w * sc);
        t[4] = __float2bfloat16(v1.x * sc); t[5] = __float2bfloat16(v1.y * sc);
        t[6] = __float2bfloat16(v1.z * sc); t[7] = __float2bfloat16(v1.w * sc);
        *(bf16x8*)(ob + k) = *(const bf16x8*)t;   // 16 B store
    }
}

// ---------------- K3: bf16 MFMA GEMM  S = 2 * X @ X^T ----------------
// X: KROWS x DDIM row-major bf16.  C: KROWS x KROWS row-major fp32.
// m97 structure: 128x128 tile, 4 waves 2x2, 16x16x32 MFMA 4x4/wave,
// global_load_lds width-16 staging, unpadded row-major LDS tiles.
__global__ __launch_bounds__(256) void gemm_mfma(const ushort* __restrict__ X,
                                                 float* __restrict__ C) {
    __shared__ ushort As[128 * 32];   // 8 KB, row-major 128x32
    __shared__ ushort Bs[128 * 32];   // 8 KB
    const int tid  = threadIdx.x;
    const int wave = tid >> 6, lane = tid & 63;
    const int wm = wave >> 1, wn = wave & 1;        // 2x2 wave grid
    const int quad = lane >> 4, l16 = lane & 15;
    const int bi = blockIdx.y, bj = blockIdx.x;

    f32x4 acc[4][4];
#pragma unroll
    for (int i = 0; i < 4; i++)
#pragma unroll
        for (int j = 0; j < 4; j++) acc[i][j] = (f32x4){0.f, 0.f, 0.f, 0.f};

    // Staging: 8 chunks of 16 rows each per tile; wave w loads chunks {w, w+4}
    // of both A and B. Lane l -> row l/4, col (l%4)*8 within chunk; LDS dest
    // is wave-uniform base + lane*16 B, matching row-major layout exactly.
    const int srow = lane >> 2;          // 0..15
    const int scol = (lane & 3) * 8;     // 0,8,16,24
    const ushort* Ag0 = X + (size_t)(bi * 128 + wave * 16       + srow) * DDIM + scol;
    const ushort* Ag1 = X + (size_t)(bi * 128 + (wave + 4) * 16 + srow) * DDIM + scol;
    const ushort* Bg0 = X + (size_t)(bj * 128 + wave * 16       + srow) * DDIM + scol;
    const ushort* Bg1 = X + (size_t)(bj * 128 + (wave + 4) * 16 + srow) * DDIM + scol;
    ushort* Al0 = As + wave * 512;        // byte offset wave*1024
    ushort* Al1 = As + (wave + 4) * 512;
    ushort* Bl0 = Bs + wave * 512;
    ushort* Bl1 = Bs + (wave + 4) * 512;

    for (int kk = 0; kk < DDIM; kk += 32) {
        __syncthreads();   // previous iter's LDS reads done before overwrite
        __builtin_amdgcn_global_load_lds(
            (const __attribute__((address_space(1))) unsigned int*)(Ag0 + kk),
            (__attribute__((address_space(3))) unsigned int*)Al0, 16, 0, 0);
        __builtin_amdgcn_global_load_lds(
            (const __attribute__((address_space(1))) unsigned int*)(Ag1 + kk),
            (__attribute__((address_space(3))) unsigned int*)Al1, 16, 0, 0);
        __builtin_amdgcn_global_load_lds(
            (const __attribute__((address_space(1))) unsigned int*)(Bg0 + kk),
            (__attribute__((address_space(3))) unsigned int*)Bl0, 16, 0, 0);
        __builtin_amdgcn_global_load_lds(
            (const __attribute__((address_space(1))) unsigned int*)(Bg1 + kk),
            (__attribute__((address_space(3))) unsigned int*)Bl1, 16, 0, 0);
        __syncthreads();   // drains vmcnt(0): staging visible

        bf16x8 a[4], b[4];
#pragma unroll
        for (int t = 0; t < 4; t++)   // A[m = l16 + tile][k = quad*8 + 0..7]
            a[t] = *(const bf16x8*)(As + (wm * 64 + t * 16 + l16) * 32 + quad * 8);
#pragma unroll
        for (int t = 0; t < 4; t++)
            b[t] = *(const bf16x8*)(Bs + (wn * 64 + t * 16 + l16) * 32 + quad * 8);
#pragma unroll
        for (int mt = 0; mt < 4; mt++)
#pragma unroll
            for (int nt = 0; nt < 4; nt++)
                acc[mt][nt] = __builtin_amdgcn_mfma_f32_16x16x32_bf16(
                    a[mt], b[nt], acc[mt][nt], 0, 0, 0);
    }

    // Epilogue: C/D layout col = lane&15, row = quad*4 + reg.  C = 2*acc.
#pragma unroll
    for (int mt = 0; mt < 4; mt++) {
#pragma unroll
        for (int r = 0; r < 4; r++) {
            const int row = bi * 128 + wm * 64 + mt * 16 + quad * 4 + r;
            float* o = C + (size_t)row * KROWS + bj * 128 + wn * 64 + l16;
#pragma unroll
            for (int nt = 0; nt < 4; nt++) o[nt * 16] = 2.0f * acc[mt][nt][r];
        }
    }
}

// ---------------- K4: per-row masked LSE + positives ----------------
__global__ void lse_kernel(const float* __restrict__ C, float* __restrict__ acc) {
    const int i = blockIdx.x;
    __shared__ float srow[KROWS];      // 8 KB
    const float* row = C + (size_t)i * KROWS;
    for (int j = threadIdx.x; j < KROWS; j += blockDim.x) srow[j] = row[j];
    __syncthreads();

    const int ires = i & (BSZ - 1);
    float m = -INFINITY;
    for (int j = threadIdx.x; j < KROWS; j += blockDim.x)
        if ((j & (BSZ - 1)) != ires) m = fmaxf(m, srow[j]);
    m = blockReduceMax(m);
    __shared__ float mS;
    if (threadIdx.x == 0) mS = m;
    __syncthreads();
    m = mS;
    float se = 0.0f;
    for (int j = threadIdx.x; j < KROWS; j += blockDim.x)
        if ((j & (BSZ - 1)) != ires) se += expf(srow[j] - m);
    se = blockReduceSum(se);

    if (threadIdx.x == 0) {
        const float neg_lse = m + logf(se);
        float loss = 0.0f;
#pragma unroll
        for (int t = 0; t < N_T; t++) {
            const int j = ires + t * BSZ;
            if (j == i) continue;
            const float x = neg_lse - srow[j];   // logaddexp(L,p)-p = softplus(L-p)
            loss += (x > 0.0f) ? (x + log1pf(expf(-x))) : log1pf(expf(x));
        }
        atomicAdd(acc + 1, loss);
    }
}

// ---------------- K5: finalize ----------------
__global__ void finalize_kernel(const float* __restrict__ acc, float* __restrict__ out) {
    if (threadIdx.x == 0 && blockIdx.x == 0)
        out[0] = acc[0] / (float)T_MSE + acc[1] / (float)KPOS;
}

extern "C" void kernel_launch(void* const* d_in, const int* in_sizes, int n_in,
                              void* d_out, int out_size, void* d_ws, size_t ws_size,
                              hipStream_t stream) {
    const float* pic = (const float*)d_in[0];
    float* dec = (float*)d_in[1];        // reusable as scratch after K1 reads it
    const float* h = (const float*)d_in[2];
    float* out = (float*)d_out;

    float* acc = (float*)d_ws;           // acc[0]=mse_sum, acc[1]=loss_h_sum
    const size_t hbuf_bytes   = (size_t)KROWS * DDIM * sizeof(__hip_bfloat16); // 16 MB
    const size_t simmat_bytes = (size_t)KROWS * KROWS * sizeof(float);         // 16 MB
    __hip_bfloat16* hbuf;
    float* simmat;
    if (ws_size >= 256 + hbuf_bytes + simmat_bytes) {
        hbuf   = (__hip_bfloat16*)((char*)d_ws + 256);
        simmat = (float*)((char*)d_ws + 256 + hbuf_bytes);
    } else {
        // dec_pics buffer (402 MB fp32) as scratch: fully consumed by
        // mse_kernel before norm/gemm write it (same stream => ordered).
        hbuf   = (__hip_bfloat16*)dec;
        simmat = (float*)((char*)dec + hbuf_bytes);
    }

    hipMemsetAsync(d_ws, 0, 256, stream);
    mse_kernel<<<2048, 256, 0, stream>>>(pic, dec, acc);
    norm_kernel<<<KROWS, 256, 0, stream>>>(h, hbuf);
    dim3 ggrid(KROWS / 128, KROWS / 128);
    gemm_mfma<<<ggrid, 256, 0, stream>>>((const ushort*)hbuf, simmat);
    lse_kernel<<<KROWS, 256, 0, stream>>>(simmat, acc);
    finalize_kernel<<<1, 64, 0, stream>>>(acc, out);
}

// Round 3
// 328.706 us; speedup vs baseline: 3.0141x; 1.0958x over previous
//
#include <hip/hip_runtime.h>
#include <hip/hip_bf16.h>
#include <math.h>

// Problem constants
#define N_T   16
#define BSZ   128
#define DDIM  4096
#define KROWS (N_T * BSZ)          // 2048
#define CHW   (3 * 64 * 64)        // 12288
#define S_PIC (BSZ * CHW)          // 1572864
#define T_MSE (N_T * S_PIC)        // 25165824
#define KPOS  (KROWS * (N_T - 1))  // 30720

typedef short  bf16x8 __attribute__((ext_vector_type(8)));   // 8 bf16 = 4 VGPRs
typedef float  f32x4  __attribute__((ext_vector_type(4)));

// ---------------- reductions ----------------
__device__ __forceinline__ float waveReduceSum(float v) {
    for (int off = 32; off > 0; off >>= 1) v += __shfl_down(v, off, 64);
    return v;
}
__device__ __forceinline__ float waveReduceMax(float v) {
    for (int off = 32; off > 0; off >>= 1) v = fmaxf(v, __shfl_down(v, off, 64));
    return v;
}
__device__ __forceinline__ float blockReduceSum(float v) {
    __shared__ float s[8];
    int lane = threadIdx.x & 63, wid = threadIdx.x >> 6;
    v = waveReduceSum(v);
    if (lane == 0) s[wid] = v;
    __syncthreads();
    int nw = (blockDim.x + 63) >> 6;
    v = (threadIdx.x < nw) ? s[threadIdx.x] : 0.0f;
    if (wid == 0) v = waveReduceSum(v);
    return v;   // valid in thread 0
}
__device__ __forceinline__ float blockReduceMax(float v) {
    __shared__ float s[8];
    int lane = threadIdx.x & 63, wid = threadIdx.x >> 6;
    v = waveReduceMax(v);
    if (lane == 0) s[wid] = v;
    __syncthreads();
    int nw = (blockDim.x + 63) >> 6;
    v = (threadIdx.x < nw) ? s[threadIdx.x] : -INFINITY;
    if (wid == 0) v = waveReduceMax(v);
    return v;   // valid in thread 0
}

// ---------------- K1: MSE with cyclic shift (m13 copy pattern) ----------------
// grid (192, 16): blockIdx.y = slab n; each block covers 256*8*4 = 8192
// contiguous floats. 16 independent float4 loads in flight per thread,
// compile-time offsets, no per-iteration division.
__global__ __launch_bounds__(256) void mse_kernel(const float* __restrict__ pic,
                                                  const float* __restrict__ dec,
                                                  float* __restrict__ acc) {
    const int n = blockIdx.y;
    const size_t off = (size_t)n * S_PIC + (size_t)blockIdx.x * 8192 + threadIdx.x * 4;
    const size_t doff = (size_t)(((n + 1) & (N_T - 1)) - n) * S_PIC;  // signed slab shift
    const float* p = pic + off;
    const float* d = dec + off + doff;
    float s0 = 0.f, s1 = 0.f, s2 = 0.f, s3 = 0.f;
#pragma unroll
    for (int k = 0; k < 8; k++) {
        float4 a = *(const float4*)(p + k * 1024);
        float4 b = *(const float4*)(d + k * 1024);
        float dx = a.x - b.x, dy = a.y - b.y, dz = a.z - b.z, dw = a.w - b.w;
        s0 += dx * dx; s1 += dy * dy; s2 += dz * dz; s3 += dw * dw;
    }
    float sum = (s0 + s1) + (s2 + s3);
    sum = blockReduceSum(sum);
    if (threadIdx.x == 0) atomicAdd(acc, sum);
}

// ---------------- K2: row normalization of h -> bf16 ----------------
__global__ void norm_kernel(const float* __restrict__ h,
                            __hip_bfloat16* __restrict__ hb) {
    const int row = blockIdx.x;
    const float* r = h + (size_t)row * DDIM;
    float ss = 0.0f;
    for (int k = threadIdx.x * 8; k < DDIM; k += blockDim.x * 8) {
        float4 v0 = *(const float4*)(r + k);
        float4 v1 = *(const float4*)(r + k + 4);
        ss += v0.x * v0.x + v0.y * v0.y + v0.z * v0.z + v0.w * v0.w;
        ss += v1.x * v1.x + v1.y * v1.y + v1.z * v1.z + v1.w * v1.w;
    }
    ss = blockReduceSum(ss);
    __shared__ float scale_s;
    if (threadIdx.x == 0) scale_s = 1.0f / fmaxf(sqrtf(ss), 1e-8f);
    __syncthreads();
    const float sc = scale_s;
    __hip_bfloat16* ob = hb + (size_t)row * DDIM;
    for (int k = threadIdx.x * 8; k < DDIM; k += blockDim.x * 8) {
        float4 v0 = *(const float4*)(r + k);
        float4 v1 = *(const float4*)(r + k + 4);
        __hip_bfloat16 t[8];
        t[0] = __float2bfloat16(v0.x * sc); t[1] = __float2bfloat16(v0.y * sc);
        t[2] = __float2bfloat16(v0.z * sc); t[3] = __float2bfloat16(v0.w * sc);
        t[4] = __float2bfloat16(v1.x * sc); t[5] = __float2bfloat16(v1.y * sc);
        t[6] = __float2bfloat16(v1.z * sc); t[7] = __float2bfloat16(v1.w * sc);
        *(bf16x8*)(ob + k) = *(const bf16x8*)t;   // 16 B store
    }
}

// ---------------- K3: bf16 MFMA GEMM  S = 2 * X @ X^T, split-K=2 ----------------
// X: KROWS x DDIM row-major bf16. Cp: 2 partial KROWS x KROWS fp32 buffers.
// m97 structure: 128x128 tile, 4 waves 2x2, 16x16x32 MFMA 4x4/wave,
// global_load_lds width-16 staging, unpadded row-major LDS tiles.
// blockIdx.z selects K-half -> 512 blocks = 2 blocks/CU co-resident, so one
// block's MFMA hides the other's vmcnt(0) barrier drain.
__global__ __launch_bounds__(256) void gemm_mfma(const ushort* __restrict__ X,
                                                 float* __restrict__ Cpart) {
    __shared__ ushort As[128 * 32];   // 8 KB, row-major 128x32
    __shared__ ushort Bs[128 * 32];   // 8 KB
    const int tid  = threadIdx.x;
    const int wave = tid >> 6, lane = tid & 63;
    const int wm = wave >> 1, wn = wave & 1;        // 2x2 wave grid
    const int quad = lane >> 4, l16 = lane & 15;
    const int bi = blockIdx.y, bj = blockIdx.x;
    const int kz = blockIdx.z;

    f32x4 acc[4][4];
#pragma unroll
    for (int i = 0; i < 4; i++)
#pragma unroll
        for (int j = 0; j < 4; j++) acc[i][j] = (f32x4){0.f, 0.f, 0.f, 0.f};

    // Staging: 8 chunks of 16 rows per tile; wave w loads chunks {w, w+4}.
    // Lane l -> row l/4, col (l%4)*8 within chunk; LDS dest is wave-uniform
    // base + lane*16 B, matching the row-major layout exactly.
    const int srow = lane >> 2;          // 0..15
    const int scol = (lane & 3) * 8;     // 0,8,16,24
    const ushort* Ag0 = X + (size_t)(bi * 128 + wave * 16       + srow) * DDIM + scol;
    const ushort* Ag1 = X + (size_t)(bi * 128 + (wave + 4) * 16 + srow) * DDIM + scol;
    const ushort* Bg0 = X + (size_t)(bj * 128 + wave * 16       + srow) * DDIM + scol;
    const ushort* Bg1 = X + (size_t)(bj * 128 + (wave + 4) * 16 + srow) * DDIM + scol;
    ushort* Al0 = As + wave * 512;
    ushort* Al1 = As + (wave + 4) * 512;
    ushort* Bl0 = Bs + wave * 512;
    ushort* Bl1 = Bs + (wave + 4) * 512;

    const int k0 = kz * (DDIM / 2), k1 = k0 + (DDIM / 2);
    for (int kk = k0; kk < k1; kk += 32) {
        __syncthreads();   // previous iter's LDS reads done before overwrite
        __builtin_amdgcn_global_load_lds(
            (const __attribute__((address_space(1))) unsigned int*)(Ag0 + kk),
            (__attribute__((address_space(3))) unsigned int*)Al0, 16, 0, 0);
        __builtin_amdgcn_global_load_lds(
            (const __attribute__((address_space(1))) unsigned int*)(Ag1 + kk),
            (__attribute__((address_space(3))) unsigned int*)Al1, 16, 0, 0);
        __builtin_amdgcn_global_load_lds(
            (const __attribute__((address_space(1))) unsigned int*)(Bg0 + kk),
            (__attribute__((address_space(3))) unsigned int*)Bl0, 16, 0, 0);
        __builtin_amdgcn_global_load_lds(
            (const __attribute__((address_space(1))) unsigned int*)(Bg1 + kk),
            (__attribute__((address_space(3))) unsigned int*)Bl1, 16, 0, 0);
        __syncthreads();   // drains vmcnt(0): staging visible

        bf16x8 a[4], b[4];
#pragma unroll
        for (int t = 0; t < 4; t++)   // A[m = l16 + tile][k = quad*8 + 0..7]
            a[t] = *(const bf16x8*)(As + (wm * 64 + t * 16 + l16) * 32 + quad * 8);
#pragma unroll
        for (int t = 0; t < 4; t++)
            b[t] = *(const bf16x8*)(Bs + (wn * 64 + t * 16 + l16) * 32 + quad * 8);
#pragma unroll
        for (int mt = 0; mt < 4; mt++)
#pragma unroll
            for (int nt = 0; nt < 4; nt++)
                acc[mt][nt] = __builtin_amdgcn_mfma_f32_16x16x32_bf16(
                    a[mt], b[nt], acc[mt][nt], 0, 0, 0);
    }

    // Epilogue: C/D layout col = lane&15, row = quad*4 + reg. Writes 2*acc
    // (the /TEMP) into this K-half's partial buffer.
    float* Cp = Cpart + (size_t)kz * KROWS * KROWS;
#pragma unroll
    for (int mt = 0; mt < 4; mt++) {
#pragma unroll
        for (int r = 0; r < 4; r++) {
            const int row = bi * 128 + wm * 64 + mt * 16 + quad * 4 + r;
            float* o = Cp + (size_t)row * KROWS + bj * 128 + wn * 64 + l16;
#pragma unroll
            for (int nt = 0; nt < 4; nt++) o[nt * 16] = 2.0f * acc[mt][nt][r];
        }
    }
}

// ---------------- K4: per-row masked LSE + positives ----------------
__global__ void lse_kernel(const float* __restrict__ Cpart, float* __restrict__ acc) {
    const int i = blockIdx.x;
    __shared__ float srow[KROWS];      // 8 KB
    const float* r0 = Cpart + (size_t)i * KROWS;
    const float* r1 = r0 + (size_t)KROWS * KROWS;
    for (int j = threadIdx.x; j < KROWS; j += blockDim.x) srow[j] = r0[j] + r1[j];
    __syncthreads();

    const int ires = i & (BSZ - 1);
    float m = -INFINITY;
    for (int j = threadIdx.x; j < KROWS; j += blockDim.x)
        if ((j & (BSZ - 1)) != ires) m = fmaxf(m, srow[j]);
    m = blockReduceMax(m);
    __shared__ float mS;
    if (threadIdx.x == 0) mS = m;
    __syncthreads();
    m = mS;
    float se = 0.0f;
    for (int j = threadIdx.x; j < KROWS; j += blockDim.x)
        if ((j & (BSZ - 1)) != ires) se += expf(srow[j] - m);
    se = blockReduceSum(se);

    if (threadIdx.x == 0) {
        const float neg_lse = m + logf(se);
        float loss = 0.0f;
#pragma unroll
        for (int t = 0; t < N_T; t++) {
            const int j = ires + t * BSZ;
            if (j == i) continue;
            const float x = neg_lse - srow[j];   // logaddexp(L,p)-p = softplus(L-p)
            loss += (x > 0.0f) ? (x + log1pf(expf(-x))) : log1pf(expf(x));
        }
        atomicAdd(acc + 1, loss);
    }
}

// ---------------- K5: finalize ----------------
__global__ void finalize_kernel(const float* __restrict__ acc, float* __restrict__ out) {
    if (threadIdx.x == 0 && blockIdx.x == 0)
        out[0] = acc[0] / (float)T_MSE + acc[1] / (float)KPOS;
}

extern "C" void kernel_launch(void* const* d_in, const int* in_sizes, int n_in,
                              void* d_out, int out_size, void* d_ws, size_t ws_size,
                              hipStream_t stream) {
    const float* pic = (const float*)d_in[0];
    float* dec = (float*)d_in[1];        // reusable as scratch after K1 reads it
    const float* h = (const float*)d_in[2];
    float* out = (float*)d_out;

    float* acc = (float*)d_ws;           // acc[0]=mse_sum, acc[1]=loss_h_sum
    const size_t hbuf_bytes   = (size_t)KROWS * DDIM * sizeof(__hip_bfloat16);     // 16 MB
    const size_t simmat_bytes = (size_t)2 * KROWS * KROWS * sizeof(float);         // 32 MB
    __hip_bfloat16* hbuf;
    float* simmat;
    if (ws_size >= 256 + hbuf_bytes + simmat_bytes) {
        hbuf   = (__hip_bfloat16*)((char*)d_ws + 256);
        simmat = (float*)((char*)d_ws + 256 + hbuf_bytes);
    } else {
        // dec_pics buffer (402 MB fp32) as scratch: fully consumed by
        // mse_kernel before norm/gemm write it (same stream => ordered).
        hbuf   = (__hip_bfloat16*)dec;
        simmat = (float*)((char*)dec + hbuf_bytes);
    }

    hipMemsetAsync(d_ws, 0, 256, stream);
    mse_kernel<<<dim3(192, N_T), 256, 0, stream>>>(pic, dec, acc);
    norm_kernel<<<KROWS, 256, 0, stream>>>(h, hbuf);
    dim3 ggrid(KROWS / 128, KROWS / 128, 2);
    gemm_mfma<<<ggrid, 256, 0, stream>>>((const ushort*)hbuf, simmat);
    lse_kernel<<<KROWS, 256, 0, stream>>>(simmat, acc);
    finalize_kernel<<<1, 64, 0, stream>>>(acc, out);
}

// Round 4
// 304.969 us; speedup vs baseline: 3.2487x; 1.0778x over previous
//
#include <hip/hip_runtime.h>
#include <hip/hip_bf16.h>
#include <math.h>

// Problem constants
#define N_T   16
#define BSZ   128
#define DDIM  4096
#define KROWS (N_T * BSZ)          // 2048
#define CHW   (3 * 64 * 64)        // 12288
#define S_PIC (BSZ * CHW)          // 1572864
#define T_MSE (N_T * S_PIC)        // 25165824
#define KPOS  (KROWS * (N_T - 1))  // 30720

#define GEMM_BLOCKS 512            // 16 x 16 tiles x split-K 2
#define MSE_BLOCKS  3072           // 16 slabs x 192 blocks

typedef short  bf16x8 __attribute__((ext_vector_type(8)));   // 8 bf16 = 4 VGPRs
typedef float  f32x4  __attribute__((ext_vector_type(4)));

// ---------------- reductions ----------------
__device__ __forceinline__ float waveReduceSum(float v) {
    for (int off = 32; off > 0; off >>= 1) v += __shfl_down(v, off, 64);
    return v;
}
__device__ __forceinline__ float waveReduceMax(float v) {
    for (int off = 32; off > 0; off >>= 1) v = fmaxf(v, __shfl_down(v, off, 64));
    return v;
}
__device__ __forceinline__ float blockReduceSum(float v) {
    __shared__ float s[8];
    int lane = threadIdx.x & 63, wid = threadIdx.x >> 6;
    v = waveReduceSum(v);
    if (lane == 0) s[wid] = v;
    __syncthreads();
    int nw = (blockDim.x + 63) >> 6;
    v = (threadIdx.x < nw) ? s[threadIdx.x] : 0.0f;
    if (wid == 0) v = waveReduceSum(v);
    return v;   // valid in thread 0
}
__device__ __forceinline__ float blockReduceMax(float v) {
    __shared__ float s[8];
    int lane = threadIdx.x & 63, wid = threadIdx.x >> 6;
    v = waveReduceMax(v);
    if (lane == 0) s[wid] = v;
    __syncthreads();
    int nw = (blockDim.x + 63) >> 6;
    v = (threadIdx.x < nw) ? s[threadIdx.x] : -INFINITY;
    if (wid == 0) v = waveReduceMax(v);
    return v;   // valid in thread 0
}

// ---------------- MSE block body (m13 copy pattern) ----------------
// Slab n, block bx: 8192 contiguous floats at n*S_PIC + bx*8192.
__device__ __forceinline__ void mse_block(const float* __restrict__ pic,
                                          const float* __restrict__ dec,
                                          float* __restrict__ acc,
                                          int n, int bx) {
    const size_t off = (size_t)n * S_PIC + (size_t)bx * 8192 + threadIdx.x * 4;
    const ptrdiff_t doff = (ptrdiff_t)(((n + 1) & (N_T - 1)) - n) * S_PIC;
    const float* p = pic + off;
    const float* d = pic + off;  // placeholder to keep types; real below
    d = dec + off + doff;
    float s0 = 0.f, s1 = 0.f, s2 = 0.f, s3 = 0.f;
#pragma unroll
    for (int k = 0; k < 8; k++) {
        float4 a = *(const float4*)(p + k * 1024);
        float4 b = *(const float4*)(d + k * 1024);
        float dx = a.x - b.x, dy = a.y - b.y, dz = a.z - b.z, dw = a.w - b.w;
        s0 += dx * dx; s1 += dy * dy; s2 += dz * dz; s3 += dw * dw;
    }
    float sum = (s0 + s1) + (s2 + s3);
    sum = blockReduceSum(sum);
    if (threadIdx.x == 0) atomicAdd(acc, sum);
}

// ---------------- K2: row normalization of h -> bf16 ----------------
__global__ void norm_kernel(const float* __restrict__ h,
                            __hip_bfloat16* __restrict__ hb) {
    const int row = blockIdx.x;
    const float* r = h + (size_t)row * DDIM;
    float ss = 0.0f;
    for (int k = threadIdx.x * 8; k < DDIM; k += blockDim.x * 8) {
        float4 v0 = *(const float4*)(r + k);
        float4 v1 = *(const float4*)(r + k + 4);
        ss += v0.x * v0.x + v0.y * v0.y + v0.z * v0.z + v0.w * v0.w;
        ss += v1.x * v1.x + v1.y * v1.y + v1.z * v1.z + v1.w * v1.w;
    }
    ss = blockReduceSum(ss);
    __shared__ float scale_s;
    if (threadIdx.x == 0) scale_s = 1.0f / fmaxf(sqrtf(ss), 1e-8f);
    __syncthreads();
    const float sc = scale_s;
    __hip_bfloat16* ob = hb + (size_t)row * DDIM;
    for (int k = threadIdx.x * 8; k < DDIM; k += blockDim.x * 8) {
        float4 v0 = *(const float4*)(r + k);
        float4 v1 = *(const float4*)(r + k + 4);
        __hip_bfloat16 t[8];
        t[0] = __float2bfloat16(v0.x * sc); t[1] = __float2bfloat16(v0.y * sc);
        t[2] = __float2bfloat16(v0.z * sc); t[3] = __float2bfloat16(v0.w * sc);
        t[4] = __float2bfloat16(v1.x * sc); t[5] = __float2bfloat16(v1.y * sc);
        t[6] = __float2bfloat16(v1.z * sc); t[7] = __float2bfloat16(v1.w * sc);
        *(bf16x8*)(ob + k) = *(const bf16x8*)t;   // 16 B store
    }
}

// ---------------- Mega kernel: fused GEMM (split-K=2) + MSE ----------------
// Blocks [0, GEMM_BLOCKS): m97-structure bf16 MFMA GEMM, S = 2 * X @ X^T into
// two partial buffers (MFMA/barrier-bound, hbuf is L2/L3-resident).
// Blocks [GEMM_BLOCKS, +MSE_BLOCKS): HBM-streaming MSE. Disjoint pipes ->
// concurrent blocks overlap (m114: MFMA + VALU/VMEM waves co-schedule).
// If n_total == GEMM_BLOCKS this is a plain GEMM launch (fallback path).
__global__ __launch_bounds__(256) void mega_kernel(const ushort* __restrict__ X,
                                                   float* __restrict__ Cpart,
                                                   const float* __restrict__ pic,
                                                   const float* __restrict__ dec,
                                                   float* __restrict__ acc) {
    __shared__ ushort As[128 * 32];   // 8 KB, row-major 128x32
    __shared__ ushort Bs[128 * 32];   // 8 KB
    const int bid = blockIdx.x;

    if (bid >= GEMM_BLOCKS) {
        const int t = bid - GEMM_BLOCKS;
        mse_block(pic, dec, acc, t & (N_T - 1), t >> 4);
        return;
    }

    // ---- GEMM path ----
    const int kz = bid >> 8;                 // split-K half
    const int bi = (bid >> 4) & 15, bj = bid & 15;
    const int tid  = threadIdx.x;
    const int wave = tid >> 6, lane = tid & 63;
    const int wm = wave >> 1, wn = wave & 1;        // 2x2 wave grid
    const int quad = lane >> 4, l16 = lane & 15;

    f32x4 acc_r[4][4];
#pragma unroll
    for (int i = 0; i < 4; i++)
#pragma unroll
        for (int j = 0; j < 4; j++) acc_r[i][j] = (f32x4){0.f, 0.f, 0.f, 0.f};

    // Staging: 8 chunks of 16 rows per tile; wave w loads chunks {w, w+4}.
    // Lane l -> row l/4, col (l%4)*8 within chunk; LDS dest is wave-uniform
    // base + lane*16 B, matching the row-major layout exactly.
    const int srow = lane >> 2;          // 0..15
    const int scol = (lane & 3) * 8;     // 0,8,16,24
    const ushort* Ag0 = X + (size_t)(bi * 128 + wave * 16       + srow) * DDIM + scol;
    const ushort* Ag1 = X + (size_t)(bi * 128 + (wave + 4) * 16 + srow) * DDIM + scol;
    const ushort* Bg0 = X + (size_t)(bj * 128 + wave * 16       + srow) * DDIM + scol;
    const ushort* Bg1 = X + (size_t)(bj * 128 + (wave + 4) * 16 + srow) * DDIM + scol;
    ushort* Al0 = As + wave * 512;
    ushort* Al1 = As + (wave + 4) * 512;
    ushort* Bl0 = Bs + wave * 512;
    ushort* Bl1 = Bs + (wave + 4) * 512;

    const int k0 = kz * (DDIM / 2), k1 = k0 + (DDIM / 2);
    for (int kk = k0; kk < k1; kk += 32) {
        __syncthreads();   // previous iter's LDS reads done before overwrite
        __builtin_amdgcn_global_load_lds(
            (const __attribute__((address_space(1))) unsigned int*)(Ag0 + kk),
            (__attribute__((address_space(3))) unsigned int*)Al0, 16, 0, 0);
        __builtin_amdgcn_global_load_lds(
            (const __attribute__((address_space(1))) unsigned int*)(Ag1 + kk),
            (__attribute__((address_space(3))) unsigned int*)Al1, 16, 0, 0);
        __builtin_amdgcn_global_load_lds(
            (const __attribute__((address_space(1))) unsigned int*)(Bg0 + kk),
            (__attribute__((address_space(3))) unsigned int*)Bl0, 16, 0, 0);
        __builtin_amdgcn_global_load_lds(
            (const __attribute__((address_space(1))) unsigned int*)(Bg1 + kk),
            (__attribute__((address_space(3))) unsigned int*)Bl1, 16, 0, 0);
        __syncthreads();   // drains vmcnt(0): staging visible

        bf16x8 a[4], b[4];
#pragma unroll
        for (int t = 0; t < 4; t++)   // A[m = l16 + tile][k = quad*8 + 0..7]
            a[t] = *(const bf16x8*)(As + (wm * 64 + t * 16 + l16) * 32 + quad * 8);
#pragma unroll
        for (int t = 0; t < 4; t++)
            b[t] = *(const bf16x8*)(Bs + (wn * 64 + t * 16 + l16) * 32 + quad * 8);
#pragma unroll
        for (int mt = 0; mt < 4; mt++)
#pragma unroll
            for (int nt = 0; nt < 4; nt++)
                acc_r[mt][nt] = __builtin_amdgcn_mfma_f32_16x16x32_bf16(
                    a[mt], b[nt], acc_r[mt][nt], 0, 0, 0);
    }

    // Epilogue: C/D layout col = lane&15, row = quad*4 + reg. Writes 2*acc
    // (the /TEMP) into this K-half's partial buffer.
    float* Cp = Cpart + (size_t)kz * KROWS * KROWS;
#pragma unroll
    for (int mt = 0; mt < 4; mt++) {
#pragma unroll
        for (int r = 0; r < 4; r++) {
            const int row = bi * 128 + wm * 64 + mt * 16 + quad * 4 + r;
            float* o = Cp + (size_t)row * KROWS + bj * 128 + wn * 64 + l16;
#pragma unroll
            for (int nt = 0; nt < 4; nt++) o[nt * 16] = 2.0f * acc_r[mt][nt][r];
        }
    }
}

// ---------------- standalone MSE (fallback sequential path) ----------------
__global__ __launch_bounds__(256) void mse_kernel(const float* __restrict__ pic,
                                                  const float* __restrict__ dec,
                                                  float* __restrict__ acc) {
    mse_block(pic, dec, acc, blockIdx.y, blockIdx.x);
}

// ---------------- K4: per-row masked LSE + positives ----------------
__global__ void lse_kernel(const float* __restrict__ Cpart, float* __restrict__ acc) {
    const int i = blockIdx.x;
    __shared__ float srow[KROWS];      // 8 KB
    const float* r0 = Cpart + (size_t)i * KROWS;
    const float* r1 = r0 + (size_t)KROWS * KROWS;
    for (int j = threadIdx.x * 4; j < KROWS; j += blockDim.x * 4) {
        float4 a = *(const float4*)(r0 + j);
        float4 b = *(const float4*)(r1 + j);
        float4 s; s.x = a.x + b.x; s.y = a.y + b.y; s.z = a.z + b.z; s.w = a.w + b.w;
        *(float4*)(srow + j) = s;
    }
    __syncthreads();

    const int ires = i & (BSZ - 1);
    float m = -INFINITY;
    for (int j = threadIdx.x; j < KROWS; j += blockDim.x)
        if ((j & (BSZ - 1)) != ires) m = fmaxf(m, srow[j]);
    m = blockReduceMax(m);
    __shared__ float mS;
    if (threadIdx.x == 0) mS = m;
    __syncthreads();
    m = mS;
    float se = 0.0f;
    for (int j = threadIdx.x; j < KROWS; j += blockDim.x)
        if ((j & (BSZ - 1)) != ires) se += expf(srow[j] - m);
    se = blockReduceSum(se);

    if (threadIdx.x == 0) {
        const float neg_lse = m + logf(se);
        float loss = 0.0f;
#pragma unroll
        for (int t = 0; t < N_T; t++) {
            const int j = ires + t * BSZ;
            if (j == i) continue;
            const float x = neg_lse - srow[j];   // logaddexp(L,p)-p = softplus(L-p)
            loss += (x > 0.0f) ? (x + log1pf(expf(-x))) : log1pf(expf(x));
        }
        atomicAdd(acc + 1, loss);
    }
}

// ---------------- K5: finalize ----------------
__global__ void finalize_kernel(const float* __restrict__ acc, float* __restrict__ out) {
    if (threadIdx.x == 0 && blockIdx.x == 0)
        out[0] = acc[0] / (float)T_MSE + acc[1] / (float)KPOS;
}

extern "C" void kernel_launch(void* const* d_in, const int* in_sizes, int n_in,
                              void* d_out, int out_size, void* d_ws, size_t ws_size,
                              hipStream_t stream) {
    const float* pic = (const float*)d_in[0];
    float* dec = (float*)d_in[1];
    const float* h = (const float*)d_in[2];
    float* out = (float*)d_out;

    float* acc = (float*)d_ws;           // acc[0]=mse_sum, acc[1]=loss_h_sum
    const size_t hbuf_bytes   = (size_t)KROWS * DDIM * sizeof(__hip_bfloat16);     // 16 MB
    const size_t simmat_bytes = (size_t)2 * KROWS * KROWS * sizeof(float);         // 32 MB

    hipMemsetAsync(d_ws, 0, 256, stream);

    if (ws_size >= 256 + hbuf_bytes + simmat_bytes) {
        // Overlapped path: MSE fused into the GEMM launch (disjoint pipes).
        __hip_bfloat16* hbuf = (__hip_bfloat16*)((char*)d_ws + 256);
        float* simmat = (float*)((char*)d_ws + 256 + hbuf_bytes);
        norm_kernel<<<KROWS, 256, 0, stream>>>(h, hbuf);
        mega_kernel<<<GEMM_BLOCKS + MSE_BLOCKS, 256, 0, stream>>>(
            (const ushort*)hbuf, simmat, pic, dec, acc);
        lse_kernel<<<KROWS, 256, 0, stream>>>(simmat, acc);
    } else {
        // Fallback: dec buffer as scratch. MSE must fully consume dec BEFORE
        // norm/gemm overwrite it -> strictly sequential kernels.
        __hip_bfloat16* hbuf = (__hip_bfloat16*)dec;
        float* simmat = (float*)((char*)dec + hbuf_bytes);
        mse_kernel<<<dim3(MSE_BLOCKS / N_T, N_T), 256, 0, stream>>>(pic, dec, acc);
        norm_kernel<<<KROWS, 256, 0, stream>>>(h, hbuf);
        mega_kernel<<<GEMM_BLOCKS, 256, 0, stream>>>(
            (const ushort*)hbuf, simmat, pic, dec, acc);
        lse_kernel<<<KROWS, 256, 0, stream>>>(simmat, acc);
    }
    finalize_kernel<<<1, 64, 0, stream>>>(acc, out);
}